// Round 13
// baseline (1082.676 us; speedup 1.0000x reference)
//
#include <hip/hip_runtime.h>
#include <hip/hip_bf16.h>

#define NB   16      // batch
#define FDIM 2048    // lstm hidden
#define GDIM 8192    // 4*FDIM gates
#define WSEQ 32      // seq len
#define CDIM 256
#define CBD  64
#define HGT  32

#define AGENTSC __HIP_MEMORY_SCOPE_AGENT

typedef float f32x4 __attribute__((ext_vector_type(4)));
typedef long  l64x2 __attribute__((ext_vector_type(2)));
typedef _Float16 f16x4 __attribute__((ext_vector_type(4)));
typedef unsigned char u8;

__device__ __forceinline__ float sigf(float x) { return 1.f / (1.f + __expf(-x)); }

__device__ __forceinline__ u8 f32_to_fp8(float f) {
    int w = __builtin_amdgcn_cvt_pk_fp8_f32(f, f, 0, 0);
    return (u8)(w & 0xff);
}

// ---------------------------------------------------------------------------
// Coalesced weight pack -> fp8 e4m3 (layout as R5-R12), 4 rows in flight.
// W[tile][kc2][lane][16B]; bytes0-7 = frag kc=2kc2, 8-15 = kc=2kc2+1;
// frag byte i of (kc,lane): k = kc*32+(lane>>4)*8+i, col = lane&15.
// ---------------------------------------------------------------------------
__global__ __launch_bounds__(256) void pack_w(
        const float* __restrict__ wih0, const float* __restrict__ whh0,
        const float* __restrict__ wih1, const float* __restrict__ whh1,
        u8* __restrict__ W0, u8* __restrict__ W1) {
    __shared__ u8 FW[16][4112];   // [c][k], +16 pad
    int b = blockIdx.x;           // 0..1023
    int mat = b >> 9, tile = b & 511;
    const float* wih = mat ? wih1 : wih0;
    const float* whh = mat ? whh1 : whh0;
    int p = tile & 1, jt = tile >> 1;
    int tid = threadIdx.x;
    for (int it = 0; it < 32; it += 4) {   // 2 src halves x 16 rows, 4-deep ILP
        float4 f[4][2];
#pragma unroll
        for (int r = 0; r < 4; ++r) {
            int c = (it + r) & 15, srcsel = (it + r) >> 4;
            int gate = p * 2 + (c >> 3);
            int rr = gate * FDIM + jt * 8 + (c & 7);
            const float* s = (srcsel ? whh : wih) + (size_t)rr * FDIM + tid * 8;
            f[r][0] = *(const float4*)(s);
            f[r][1] = *(const float4*)(s + 4);
        }
#pragma unroll
        for (int r = 0; r < 4; ++r) {
            int c = (it + r) & 15, srcsel = (it + r) >> 4;
            int w0 = __builtin_amdgcn_cvt_pk_fp8_f32(f[r][0].x, f[r][0].y, 0, 0);
            w0     = __builtin_amdgcn_cvt_pk_fp8_f32(f[r][0].z, f[r][0].w, w0, 1);
            int w1 = __builtin_amdgcn_cvt_pk_fp8_f32(f[r][1].x, f[r][1].y, 0, 0);
            w1     = __builtin_amdgcn_cvt_pk_fp8_f32(f[r][1].z, f[r][1].w, w1, 1);
            *(int2*)&FW[c][srcsel * 2048 + tid * 8] = make_int2(w0, w1);
        }
    }
    __syncthreads();
    u8* base = (mat ? W1 : W0) + (size_t)tile * 65536;
#pragma unroll
    for (int w = 0; w < 16; ++w) {
        int q = w * 256 + tid;            // kc2*64 + lane
        int kc2 = q >> 6, lane = q & 63;
        int c = lane & 15, kg = lane >> 4;
        l64x2 v;
        v.x = *(const long*)&FW[c][kc2 * 64 + kg * 8];
        v.y = *(const long*)&FW[c][kc2 * 64 + 32 + kg * 8];
        *(l64x2*)(base + (size_t)q * 16) = v;
    }
}

__global__ void bias_k(const float* __restrict__ bih0, const float* __restrict__ bhh0,
                       const float* __restrict__ bih1, const float* __restrict__ bhh1,
                       float* __restrict__ b0, float* __restrict__ b1) {
    int i = blockIdx.x * blockDim.x + threadIdx.x;
    if (i < GDIM)            b0[i] = bih0[i] + bhh0[i];
    else if (i < 2 * GDIM) { int j = i - GDIM; b1[j] = bih1[j] + bhh1[j]; }
}

// ---------------------------------------------------------------------------
// 1x1 conv-in; emit seq in PACKED A-fragment layout:
//   seqbP[t] : [64 kc][64 lane][8B], byte i of (kc,lane): k = kc*32+(lane>>4)*8+i
// ---------------------------------------------------------------------------
__global__ __launch_bounds__(256) void conv_in(const float* __restrict__ latent,
                        const float* __restrict__ w_in, const float* __restrict__ b_in,
                        u8* __restrict__ seqbP) {
    __shared__ float lat[CDIM * HGT]; // [c][h] 32 KiB
    __shared__ float hv[FDIM];        // 8 KiB
    int b = blockIdx.x; int n = b >> 5; int t = b & 31;
    int tid = threadIdx.x;
    for (int i = 0; i < 32; ++i) {
        int flat = i * 256 + tid;         // c*32+h
        int c = flat >> 5, h = flat & 31;
        lat[flat] = latent[(((size_t)n * CDIM + c) * WSEQ + t) * HGT + h];
    }
    __syncthreads();
    int cb = tid & 63;
    int hb = tid >> 6;
    float acc[8];
#pragma unroll
    for (int k = 0; k < 8; ++k) acc[k] = b_in[cb];
    for (int c = 0; c < CDIM; ++c) {
        float wv = w_in[cb * CDIM + c];
#pragma unroll
        for (int k = 0; k < 8; ++k) acc[k] += lat[c * HGT + (hb + k * 4)] * wv;
    }
#pragma unroll
    for (int k = 0; k < 8; ++k) hv[k * 256 + tid] = acc[k];   // hv[f], f = h*64+cb
    __syncthreads();
    union { u8 by[8]; long l; } pk;
#pragma unroll
    for (int i = 0; i < 8; ++i) pk.by[i] = f32_to_fp8(hv[tid * 8 + i]);
    *(long*)(seqbP + (size_t)t * 32768 + (tid >> 2) * 512 + (tid & 3) * 128 + n * 8) = pk.l;
}

// ---------------------------------------------------------------------------
// Async 8x8B PLAIN (L2-cached) load cluster, chunk stride 512B, no waits.
// Safe: every activation address is written exactly once (fresh per stage)
// before its consuming stage -> no stale L2 lines possible.
// ---------------------------------------------------------------------------
__device__ __forceinline__ void load8_plain(const u8* p, long* f) {
    asm volatile("global_load_dwordx2 %0, %1, off"             : "=v"(f[0]) : "v"(p));
    asm volatile("global_load_dwordx2 %0, %1, off offset:512"  : "=v"(f[1]) : "v"(p));
    asm volatile("global_load_dwordx2 %0, %1, off offset:1024" : "=v"(f[2]) : "v"(p));
    asm volatile("global_load_dwordx2 %0, %1, off offset:1536" : "=v"(f[3]) : "v"(p));
    asm volatile("global_load_dwordx2 %0, %1, off offset:2048" : "=v"(f[4]) : "v"(p));
    asm volatile("global_load_dwordx2 %0, %1, off offset:2560" : "=v"(f[5]) : "v"(p));
    asm volatile("global_load_dwordx2 %0, %1, off offset:3072" : "=v"(f[6]) : "v"(p));
    asm volatile("global_load_dwordx2 %0, %1, off offset:3584" : "=v"(f[7]) : "v"(p));
}

__device__ __forceinline__ void vm_wait0() {
    asm volatile("s_waitcnt vmcnt(0)" ::: "memory");
    __builtin_amdgcn_sched_barrier(0);
}

// lgkm-only block sync (does NOT drain vmcnt)
__device__ __forceinline__ void sync_lds() {
    asm volatile("s_waitcnt lgkmcnt(0)" ::: "memory");
    __builtin_amdgcn_s_barrier();
    asm volatile("" ::: "memory");
}

__device__ __forceinline__ f32x4 mfma8(long a, long b, f32x4 acc) {
    return __builtin_amdgcn_mfma_f32_16x16x32_fp8_fp8(a, b, acc, 0, 0, 0);
}

__device__ __forceinline__ void mma8_reg(const long* f, const l64x2* b, f32x4& acc) {
#pragma unroll
    for (int i = 0; i < 4; ++i) {
        acc = mfma8(f[2 * i],     b[i].x, acc);
        acc = mfma8(f[2 * i + 1], b[i].y, acc);
    }
}

// fp16 partials: P[t][w][col(la)][m pad20]; one 8B ds_write per frag.
__device__ __forceinline__ void store_frag(_Float16* P, int t, int w,
                                           int kg, int la, f32x4 acc) {
    f16x4 h;
#pragma unroll
    for (int q = 0; q < 4; ++q) h[q] = (_Float16)acc[q];
    *(f16x4*)&P[(((t * 16 + w) * 16) + la) * 20 + kg * 4] = h;
}

// LSTM cell tail: 16-deep fp16 partial reduce; cell state in regs; h -> one
// fresh 32KiB buffer via sc1 byte store (straight to L3, never dirty L2).
// t2 = local thread index 0..127 -> (m = t2>>3, jj = t2&7).
__device__ __forceinline__ void cell_tail16(const _Float16* P, int jt, int t2,
        float bi, float bf, float bg, float bo, float& cr,
        u8* hOut, float* seqSlot) {
    int m = t2 >> 3, jj = t2 & 7;
    float gi = 0.f, gf = 0.f, gg = 0.f, go = 0.f;
#pragma unroll
    for (int w2 = 0; w2 < 16; ++w2) {
        int i0 = (w2 * 16 + jj) * 20 + m;
        gi += (float)P[i0];
        gf += (float)P[i0 + 160];
        gg += (float)P[i0 + 5120];
        go += (float)P[i0 + 5280];
    }
    float cn = sigf(gf + bf) * cr + sigf(gi + bi) * tanhf(gg + bg);
    float h  = sigf(go + bo) * tanhf(cn);
    cr = cn;
    u8 hb = f32_to_fp8(h);
    int pos = (jt >> 2) * 512 + (jt & 3) * 128 + t2;
    __hip_atomic_store(hOut + pos, hb, __ATOMIC_RELAXED, AGENTSC);
    if (seqSlot)
        __hip_atomic_store(seqSlot + m * FDIM + jt * 8 + jj, h,
                           __ATOMIC_RELAXED, AGENTSC);
}

// ---------------------------------------------------------------------------
// Store-slot grid barrier: per-stage arr[k][256]. Arrival = ONE sc1 store.
// Wave 0 polls all 256 slots (1 dwordx4 per lane). Entry __syncthreads
// drains each wave's sc1 h-stores (compiler emits vmcnt(0) before s_barrier).
// ---------------------------------------------------------------------------
__device__ __forceinline__ void grid_bar(unsigned* slots) {
    __syncthreads();
    if (threadIdx.x < 64) {
        if (threadIdx.x == 0) {
            unsigned one = 1u;
            const unsigned* p = slots + blockIdx.x;
            asm volatile("global_store_dword %0, %1, off sc1"
                         :: "v"(p), "v"(one) : "memory");
        }
        const uint4* q = (const uint4*)slots + threadIdx.x;
        int guard = 0;
        while (++guard < (1 << 22)) {
            uint4 v;
            asm volatile("global_load_dwordx4 %0, %1, off sc1"
                         : "=v"(v) : "v"(q) : "memory");
            asm volatile("s_waitcnt vmcnt(0)" ::: "memory");
            if (__all((v.x & v.y & v.z & v.w) != 0u)) break;
            __builtin_amdgcn_s_sleep(1);
        }
    }
    __syncthreads();
}

// ---------------------------------------------------------------------------
// Persistent recurrence. 256 blocks x 1024 thr (1 block/CU, enforced via LDS
// pad). Block jt owns features jt*8..jt*8+7 for all 4 gates. Wave w covers K
// chunks w*8..w*8+7 for both gate-pair tiles. BOTH W0 and W1 slices pinned in
// registers (no weight memory traffic, no W1 LDS). LDS = two fp16 partial
// sets only. Fwd stage: single sync, L0/L1 cell tails run in PARALLEL
// (tid<128 owns cr0, tid 128-255 owns cr1). Activations rotate through
// per-stage fresh buffers (plain L2-cached reads, sc1 writes). AR: stale
// half pre-issued before grid_bar so only the fresh half is exposed.
// ---------------------------------------------------------------------------
__global__ __launch_bounds__(1024, 4) void recurrence(
        const u8* __restrict__ W0, const u8* __restrict__ W1,
        const u8* __restrict__ seqbP,
        const float* __restrict__ b0, const float* __restrict__ b1,
        u8* __restrict__ h0buf, u8* __restrict__ h1buf,
        const u8* __restrict__ zb,
        float* __restrict__ sqo, unsigned* __restrict__ arr) {
    __shared__ _Float16 pA[2 * 16 * 16 * 20];  // 20 KiB L0 partials
    __shared__ _Float16 pB[2 * 16 * 16 * 20];  // 20 KiB L1 partials
    __shared__ u8 ldspad[49152];               // force 1 block/CU (88 KiB total)
    const int jt = blockIdx.x, tid = threadIdx.x;
    const int w = tid >> 6, l = tid & 63;
    const int la = l & 15, kg = l >> 4;
    if (tid == 1023) { volatile u8* vp = ldspad; vp[0] = 1; }
    // pin W0,W1: tiles jt*2+t, kc2 = w*4..w*4+3
    l64x2 w0pin[8], w1pin[8];
#pragma unroll
    for (int t = 0; t < 2; ++t)
#pragma unroll
        for (int i = 0; i < 4; ++i) {
            size_t idx = ((size_t)((jt * 2 + t) * 64 + w * 4 + i) * 64 + l) * 16;
            w0pin[t * 4 + i] = *(const l64x2*)(W0 + idx);
            w1pin[t * 4 + i] = *(const l64x2*)(W1 + idx);
        }
    float cr = 0.f;          // cr0 on tid<128, cr1 on tid 128..255
    float bi = 0, bf = 0, bg = 0, bo = 0;
    if (tid < 128) {
        int j = jt * 8 + (tid & 7);
        bi = b0[j]; bf = b0[FDIM + j]; bg = b0[2 * FDIM + j]; bo = b0[3 * FDIM + j];
    } else if (tid < 256) {
        int j = jt * 8 + (tid & 7);
        bi = b1[j]; bf = b1[FDIM + j]; bg = b1[2 * FDIM + j]; bo = b1[3 * FDIM + j];
    }
    __syncthreads();

    unsigned* bs = arr;
    const f32x4 z = {0.f, 0.f, 0.f, 0.f};
    const size_t wl = (size_t)w * 4096 + (size_t)l * 8;        // waves 0-7
    const size_t wh = (size_t)(w - 8) * 4096 + (size_t)l * 8;  // waves 8-15
#define H0(s) (h0buf + (size_t)(s) * 32768)
#define H1(s) (h1buf + (size_t)(s) * 32768)

    long f0[8], f1[8];

    // ---- stage 0 region: L0[0] (x = seqbP[0], h = zeros) ----
    {
        load8_plain((w < 8) ? seqbP + wl : zb + wh, f0);
        vm_wait0();
        f32x4 t0 = z, t1 = z;
        mma8_reg(f0, w0pin, t0); mma8_reg(f0, w0pin + 4, t1);
        store_frag(pA, 0, w, kg, la, t0);
        store_frag(pA, 1, w, kg, la, t1);
        sync_lds();
        if (tid < 128)
            cell_tail16(pA, jt, tid, bi, bf, bg, bo, cr, H0(0), nullptr);
    }
    // ---- fwd stages s=0..30: L0[s+1] + L1[s], single sync, parallel tails ----
    for (int s = 0; s <= 30; ++s) {
        if (w < 8) load8_plain(seqbP + (size_t)(s + 1) * 32768 + wl, f0); // static, pre-bar
        grid_bar(bs); bs += 256;
        if (w >= 8) {
            load8_plain(H0(s) + wh, f0);                          // fresh h0[s]
            load8_plain((s ? H1(s - 1) : zb) + wh, f1);           // fresh h1[s-1]
        } else {
            load8_plain(H0(s) + wl, f1);                          // fresh h0[s]
        }
        vm_wait0();
        f32x4 q00 = z, q01 = z, q10 = z, q11 = z;
        mma8_reg(f0, w0pin, q00); mma8_reg(f0, w0pin + 4, q01);
        mma8_reg(f1, w1pin, q10); mma8_reg(f1, w1pin + 4, q11);
        store_frag(pA, 0, w, kg, la, q00);
        store_frag(pA, 1, w, kg, la, q01);
        store_frag(pB, 0, w, kg, la, q10);
        store_frag(pB, 1, w, kg, la, q11);
        sync_lds();
        if (tid < 128)
            cell_tail16(pA, jt, tid, bi, bf, bg, bo, cr, H0(s + 1), nullptr);
        else if (tid < 256)
            cell_tail16(pB, jt, tid - 128, bi, bf, bg, bo, cr, H1(s), nullptr);
    }
    // ---- L1[31]: first recorded output ----
    {
        grid_bar(bs); bs += 256;
        load8_plain((w < 8) ? H0(31) + wl : H1(30) + wh, f1);
        vm_wait0();
        f32x4 t0 = z, t1 = z;
        mma8_reg(f1, w1pin, t0); mma8_reg(f1, w1pin + 4, t1);
        store_frag(pB, 0, w, kg, la, t0);
        store_frag(pB, 1, w, kg, la, t1);
        sync_lds();
        if (tid >= 128 && tid < 256)
            cell_tail16(pB, jt, tid - 128, bi, bf, bg, bo, cr, H1(31), sqo);
    }
    // ---- AR region s=32..62 ----
    for (int s = 32; s < 63; ++s) {
        // L0[s]: x = h1[s-1] (fresh, w<8), h0[s-1] (stale, w>=8, PRE-issued)
        if (w >= 8) load8_plain(H0(s - 1) + wh, f0);
        grid_bar(bs); bs += 256;
        if (w < 8) load8_plain(H1(s - 1) + wl, f0);
        vm_wait0();
        {
            f32x4 t0 = z, t1 = z;
            mma8_reg(f0, w0pin, t0); mma8_reg(f0, w0pin + 4, t1);
            store_frag(pA, 0, w, kg, la, t0);
            store_frag(pA, 1, w, kg, la, t1);
            sync_lds();
            if (tid < 128)
                cell_tail16(pA, jt, tid, bi, bf, bg, bo, cr, H0(s), nullptr);
        }
        // L1[s]: h0[s] (fresh, w<8), h1[s-1] (stale, w>=8, PRE-issued)
        if (w >= 8) load8_plain(H1(s - 1) + wh, f1);
        grid_bar(bs); bs += 256;
        if (w < 8) load8_plain(H0(s) + wl, f1);
        vm_wait0();
        {
            f32x4 t0 = z, t1 = z;
            mma8_reg(f1, w1pin, t0); mma8_reg(f1, w1pin + 4, t1);
            store_frag(pB, 0, w, kg, la, t0);
            store_frag(pB, 1, w, kg, la, t1);
            sync_lds();
            if (tid >= 128 && tid < 256)
                cell_tail16(pB, jt, tid - 128, bi, bf, bg, bo, cr, H1(s),
                            sqo + (size_t)(s - 31) * NB * FDIM);
        }
    }
#undef H0
#undef H1
}

// copy latent -> out[:, :, 0:32, :]
__global__ void copy_lat(const float* __restrict__ latent, float* __restrict__ out) {
    size_t i = (size_t)blockIdx.x * blockDim.x + threadIdx.x;
    if (i >= (size_t)1048576) return;
    size_t blk = i >> 8;
    size_t within = i & 255;
    float4 v = ((const float4*)latent)[i];
    ((float4*)out)[blk * 512 + within] = v;
}

// gen half: out[n][c][32+t][h] = sum_cb seq_out[t][n][h*64+cb]*w_out[c][cb] + b_out[c]
__global__ __launch_bounds__(256) void gen_out(const float* __restrict__ seq_out,
                        const float* __restrict__ w_out, const float* __restrict__ b_out,
                        float* __restrict__ out) {
    __shared__ float row[32 * 65];
    int b = blockIdx.x; int n = b >> 5, t = b & 31;
    const float* src = seq_out + ((size_t)t * NB + n) * FDIM;
    for (int i = threadIdx.x; i < FDIM; i += 256)
        row[(i >> 6) * 65 + (i & 63)] = src[i];
    __syncthreads();
    for (int it = 0; it < 32; ++it) {
        int o = it * 256 + threadIdx.x;
        int c = o >> 5, h = o & 31;
        float acc = b_out[c];
#pragma unroll
        for (int cb = 0; cb < CBD; ++cb) acc += row[h * 65 + cb] * w_out[c * CBD + cb];
        out[(((size_t)n * CDIM + c) * 64 + 32 + t) * HGT + h] = acc;
    }
}

extern "C" void kernel_launch(void* const* d_in, const int* in_sizes, int n_in,
                              void* d_out, int out_size, void* d_ws, size_t ws_size,
                              hipStream_t stream) {
    const float* latent = (const float*)d_in[0];
    const float* w_in   = (const float*)d_in[1];
    const float* b_in   = (const float*)d_in[2];
    const float* w_ih0  = (const float*)d_in[3];
    const float* w_hh0  = (const float*)d_in[4];
    const float* b_ih0  = (const float*)d_in[5];
    const float* b_hh0  = (const float*)d_in[6];
    const float* w_ih1  = (const float*)d_in[7];
    const float* w_hh1  = (const float*)d_in[8];
    const float* b_ih1  = (const float*)d_in[9];
    const float* b_hh1  = (const float*)d_in[10];
    const float* w_out  = (const float*)d_in[11];
    const float* b_out  = (const float*)d_in[12];
    float* out = (float*)d_out;
    char* ws = (char*)d_ws;

    size_t off = 0;
    u8*    W0   = (u8*)(ws + off); off += (size_t)512 * 65536;             // 32 MiB
    u8*    W1   = (u8*)(ws + off); off += (size_t)512 * 65536;             // 32 MiB
    u8*    seqbP= (u8*)(ws + off); off += (size_t)WSEQ * 32768;            // 1 MiB
    float* sqo  = (float*)(ws + off); off += (size_t)WSEQ * NB * FDIM * 4; // 4 MiB
    u8*    h0buf= (u8*)(ws + off); off += (size_t)64 * 32768;              // 2 MiB
    u8*    h1buf= (u8*)(ws + off); off += (size_t)64 * 32768;              // 2 MiB
    char*  zbase = ws + off;
    u8*    zb   = (u8*)(ws + off); off += 32768;                           // zeros
    unsigned* arr = (unsigned*)(ws + off); off += (size_t)94 * 1024;       // 94 KiB
    size_t zbytes = (size_t)(ws + off - zbase);
    float* b0 = (float*)(ws + off); off += (size_t)GDIM * 4;
    float* b1 = (float*)(ws + off); off += (size_t)GDIM * 4;

    if (ws_size < off) {
        hipMemsetAsync(d_out, 0, (size_t)out_size * 4, stream);
        return;
    }

    hipMemsetAsync(zbase, 0, zbytes, stream);
    pack_w<<<1024, 256, 0, stream>>>(w_ih0, w_hh0, w_ih1, w_hh1, W0, W1);
    bias_k<<<64, 256, 0, stream>>>(b_ih0, b_hh0, b_ih1, b_hh1, b0, b1);
    conv_in<<<512, 256, 0, stream>>>(latent, w_in, b_in, seqbP);
    recurrence<<<256, 1024, 0, stream>>>(W0, W1, seqbP, b0, b1,
                                         h0buf, h1buf, zb, sqo, arr);
    copy_lat<<<4096, 256, 0, stream>>>(latent, out);
    gen_out<<<512, 256, 0, stream>>>(sqo, w_out, b_out, out);
}

// Round 14
// 809.702 us; speedup vs baseline: 1.3371x; 1.3371x over previous
//
#include <hip/hip_runtime.h>
#include <hip/hip_bf16.h>

#define NB   16      // batch
#define FDIM 2048    // lstm hidden
#define GDIM 8192    // 4*FDIM gates
#define WSEQ 32      // seq len
#define CDIM 256
#define CBD  64
#define HGT  32

#define AGENTSC __HIP_MEMORY_SCOPE_AGENT

typedef float f32x4 __attribute__((ext_vector_type(4)));
typedef long  l64x2 __attribute__((ext_vector_type(2)));
typedef _Float16 f16x4 __attribute__((ext_vector_type(4)));
typedef unsigned char u8;

__device__ __forceinline__ float sigf(float x) { return 1.f / (1.f + __expf(-x)); }

__device__ __forceinline__ u8 f32_to_fp8(float f) {
    int w = __builtin_amdgcn_cvt_pk_fp8_f32(f, f, 0, 0);
    return (u8)(w & 0xff);
}

// ---------------------------------------------------------------------------
// Coalesced weight pack -> fp8 e4m3 (layout as R5-R13), 4 rows in flight.
// W[tile][kc2][lane][16B]; bytes0-7 = frag kc=2kc2, 8-15 = kc=2kc2+1;
// frag byte i of (kc,lane): k = kc*32+(lane>>4)*8+i, col = lane&15.
// ---------------------------------------------------------------------------
__global__ __launch_bounds__(256) void pack_w(
        const float* __restrict__ wih0, const float* __restrict__ whh0,
        const float* __restrict__ wih1, const float* __restrict__ whh1,
        u8* __restrict__ W0, u8* __restrict__ W1) {
    __shared__ u8 FW[16][4112];   // [c][k], +16 pad
    int b = blockIdx.x;           // 0..1023
    int mat = b >> 9, tile = b & 511;
    const float* wih = mat ? wih1 : wih0;
    const float* whh = mat ? whh1 : whh0;
    int p = tile & 1, jt = tile >> 1;
    int tid = threadIdx.x;
    for (int it = 0; it < 32; it += 4) {   // 2 src halves x 16 rows, 4-deep ILP
        float4 f[4][2];
#pragma unroll
        for (int r = 0; r < 4; ++r) {
            int c = (it + r) & 15, srcsel = (it + r) >> 4;
            int gate = p * 2 + (c >> 3);
            int rr = gate * FDIM + jt * 8 + (c & 7);
            const float* s = (srcsel ? whh : wih) + (size_t)rr * FDIM + tid * 8;
            f[r][0] = *(const float4*)(s);
            f[r][1] = *(const float4*)(s + 4);
        }
#pragma unroll
        for (int r = 0; r < 4; ++r) {
            int c = (it + r) & 15, srcsel = (it + r) >> 4;
            int w0 = __builtin_amdgcn_cvt_pk_fp8_f32(f[r][0].x, f[r][0].y, 0, 0);
            w0     = __builtin_amdgcn_cvt_pk_fp8_f32(f[r][0].z, f[r][0].w, w0, 1);
            int w1 = __builtin_amdgcn_cvt_pk_fp8_f32(f[r][1].x, f[r][1].y, 0, 0);
            w1     = __builtin_amdgcn_cvt_pk_fp8_f32(f[r][1].z, f[r][1].w, w1, 1);
            *(int2*)&FW[c][srcsel * 2048 + tid * 8] = make_int2(w0, w1);
        }
    }
    __syncthreads();
    u8* base = (mat ? W1 : W0) + (size_t)tile * 65536;
#pragma unroll
    for (int w = 0; w < 16; ++w) {
        int q = w * 256 + tid;            // kc2*64 + lane
        int kc2 = q >> 6, lane = q & 63;
        int c = lane & 15, kg = lane >> 4;
        l64x2 v;
        v.x = *(const long*)&FW[c][kc2 * 64 + kg * 8];
        v.y = *(const long*)&FW[c][kc2 * 64 + 32 + kg * 8];
        *(l64x2*)(base + (size_t)q * 16) = v;
    }
}

__global__ void bias_k(const float* __restrict__ bih0, const float* __restrict__ bhh0,
                       const float* __restrict__ bih1, const float* __restrict__ bhh1,
                       float* __restrict__ b0, float* __restrict__ b1) {
    int i = blockIdx.x * blockDim.x + threadIdx.x;
    if (i < GDIM)            b0[i] = bih0[i] + bhh0[i];
    else if (i < 2 * GDIM) { int j = i - GDIM; b1[j] = bih1[j] + bhh1[j]; }
}

// ---------------------------------------------------------------------------
// 1x1 conv-in; emit seq in PACKED A-fragment layout:
//   seqbP[t] : [64 kc][64 lane][8B], byte i of (kc,lane): k = kc*32+(lane>>4)*8+i
// ---------------------------------------------------------------------------
__global__ __launch_bounds__(256) void conv_in(const float* __restrict__ latent,
                        const float* __restrict__ w_in, const float* __restrict__ b_in,
                        u8* __restrict__ seqbP) {
    __shared__ float lat[CDIM * HGT]; // [c][h] 32 KiB
    __shared__ float hv[FDIM];        // 8 KiB
    int b = blockIdx.x; int n = b >> 5; int t = b & 31;
    int tid = threadIdx.x;
    for (int i = 0; i < 32; ++i) {
        int flat = i * 256 + tid;         // c*32+h
        int c = flat >> 5, h = flat & 31;
        lat[flat] = latent[(((size_t)n * CDIM + c) * WSEQ + t) * HGT + h];
    }
    __syncthreads();
    int cb = tid & 63;
    int hb = tid >> 6;
    float acc[8];
#pragma unroll
    for (int k = 0; k < 8; ++k) acc[k] = b_in[cb];
    for (int c = 0; c < CDIM; ++c) {
        float wv = w_in[cb * CDIM + c];
#pragma unroll
        for (int k = 0; k < 8; ++k) acc[k] += lat[c * HGT + (hb + k * 4)] * wv;
    }
#pragma unroll
    for (int k = 0; k < 8; ++k) hv[k * 256 + tid] = acc[k];   // hv[f], f = h*64+cb
    __syncthreads();
    union { u8 by[8]; long l; } pk;
#pragma unroll
    for (int i = 0; i < 8; ++i) pk.by[i] = f32_to_fp8(hv[tid * 8 + i]);
    *(long*)(seqbP + (size_t)t * 32768 + (tid >> 2) * 512 + (tid & 3) * 128 + n * 8) = pk.l;
}

// ---------------------------------------------------------------------------
// Async 8x8B PLAIN (L2-cached) load cluster, chunk stride 512B, no waits.
// Safe: every activation address is written exactly once (fresh per stage)
// before its consuming stage -> no stale L2 lines possible.
// ---------------------------------------------------------------------------
__device__ __forceinline__ void load8_plain(const u8* p, long* f) {
    asm volatile("global_load_dwordx2 %0, %1, off"             : "=v"(f[0]) : "v"(p));
    asm volatile("global_load_dwordx2 %0, %1, off offset:512"  : "=v"(f[1]) : "v"(p));
    asm volatile("global_load_dwordx2 %0, %1, off offset:1024" : "=v"(f[2]) : "v"(p));
    asm volatile("global_load_dwordx2 %0, %1, off offset:1536" : "=v"(f[3]) : "v"(p));
    asm volatile("global_load_dwordx2 %0, %1, off offset:2048" : "=v"(f[4]) : "v"(p));
    asm volatile("global_load_dwordx2 %0, %1, off offset:2560" : "=v"(f[5]) : "v"(p));
    asm volatile("global_load_dwordx2 %0, %1, off offset:3072" : "=v"(f[6]) : "v"(p));
    asm volatile("global_load_dwordx2 %0, %1, off offset:3584" : "=v"(f[7]) : "v"(p));
}

__device__ __forceinline__ void vm_wait0() {
    asm volatile("s_waitcnt vmcnt(0)" ::: "memory");
    __builtin_amdgcn_sched_barrier(0);
}

// lgkm-only block sync (does NOT drain vmcnt)
__device__ __forceinline__ void sync_lds() {
    asm volatile("s_waitcnt lgkmcnt(0)" ::: "memory");
    __builtin_amdgcn_s_barrier();
    asm volatile("" ::: "memory");
}

__device__ __forceinline__ f32x4 mfma8(long a, long b, f32x4 acc) {
    return __builtin_amdgcn_mfma_f32_16x16x32_fp8_fp8(a, b, acc, 0, 0, 0);
}

__device__ __forceinline__ void mma8_reg(const long* f, const l64x2* b, f32x4& acc) {
#pragma unroll
    for (int i = 0; i < 4; ++i) {
        acc = mfma8(f[2 * i],     b[i].x, acc);
        acc = mfma8(f[2 * i + 1], b[i].y, acc);
    }
}
__device__ __forceinline__ void mma8_lds(const long* f, const l64x2* bb, f32x4& acc) {
#pragma unroll
    for (int i = 0; i < 4; ++i) {
        l64x2 bl = bb[(size_t)i * 64];
        acc = mfma8(f[2 * i],     bl.x, acc);
        acc = mfma8(f[2 * i + 1], bl.y, acc);
    }
}

// fp16 partials, pad-16: P[t][w][col(la)][m]; one 8B ds_write per frag.
__device__ __forceinline__ void store_frag(_Float16* P, int t, int w,
                                           int kg, int la, f32x4 acc) {
    f16x4 h;
#pragma unroll
    for (int q = 0; q < 4; ++q) h[q] = (_Float16)acc[q];
    *(f16x4*)&P[(((t * 16 + w) * 16) + la) * 16 + kg * 4] = h;
}

// LSTM cell tail: 16-deep fp16 partial reduce; cell state in regs; h -> one
// fresh 32KiB buffer via sc1 byte store. t2 = local idx 0..127.
__device__ __forceinline__ void cell_tail16(const _Float16* P, int jt, int t2,
        float bi, float bf, float bg, float bo, float& cr,
        u8* hOut, float* seqSlot) {
    int m = t2 >> 3, jj = t2 & 7;
    float gi = 0.f, gf = 0.f, gg = 0.f, go = 0.f;
#pragma unroll
    for (int w2 = 0; w2 < 16; ++w2) {
        int i0 = (w2 * 16 + jj) * 16 + m;
        gi += (float)P[i0];
        gf += (float)P[i0 + 128];
        gg += (float)P[i0 + 4096];
        go += (float)P[i0 + 4224];
    }
    float cn = sigf(gf + bf) * cr + sigf(gi + bi) * tanhf(gg + bg);
    float h  = sigf(go + bo) * tanhf(cn);
    cr = cn;
    u8 hb = f32_to_fp8(h);
    int pos = (jt >> 2) * 512 + (jt & 3) * 128 + t2;
    __hip_atomic_store(hOut + pos, hb, __ATOMIC_RELAXED, AGENTSC);
    if (seqSlot)
        __hip_atomic_store(seqSlot + m * FDIM + jt * 8 + jj, h,
                           __ATOMIC_RELAXED, AGENTSC);
}

// ---------------------------------------------------------------------------
// Store-slot grid barrier: per-stage arr[k][256]. Arrival = ONE sc1 store.
// Wave 0 polls all 256 slots (1 dwordx4 per lane). Entry __syncthreads
// drains each wave's sc1 h-stores (compiler emits vmcnt(0) before s_barrier).
// ---------------------------------------------------------------------------
__device__ __forceinline__ void grid_bar(unsigned* slots) {
    __syncthreads();
    if (threadIdx.x < 64) {
        if (threadIdx.x == 0) {
            unsigned one = 1u;
            const unsigned* p = slots + blockIdx.x;
            asm volatile("global_store_dword %0, %1, off sc1"
                         :: "v"(p), "v"(one) : "memory");
        }
        const uint4* q = (const uint4*)slots + threadIdx.x;
        int guard = 0;
        while (++guard < (1 << 22)) {
            uint4 v;
            asm volatile("global_load_dwordx4 %0, %1, off sc1"
                         : "=v"(v) : "v"(q) : "memory");
            asm volatile("s_waitcnt vmcnt(0)" ::: "memory");
            if (__all((v.x & v.y & v.z & v.w) != 0u)) break;
            __builtin_amdgcn_s_sleep(1);
        }
    }
    __syncthreads();
}

// ---------------------------------------------------------------------------
// Persistent recurrence. 256 blocks x 1024 thr (1 block/CU). Block jt owns
// features jt*8..jt*8+7 for all 4 gates. Wave w covers K chunks w*8..w*8+7
// for both gate-pair tiles. W0 slice pinned in regs (16 VGPR), W1 slice in
// LDS (128 KiB) -- R12's proven budget. Two 16 KiB fp16 partial sets allow
// SINGLE-sync stages with PARALLEL cell tails (tid<128: L0/cr0, tid 128-255:
// L1/cr1). Activations rotate through per-stage fresh buffers (plain
// L2-cached reads, sc1 writes). AR: stale half pre-issued during the
// previous phase so only the fresh half is exposed post-barrier.
// ---------------------------------------------------------------------------
__global__ __launch_bounds__(1024, 4) void recurrence(
        const u8* __restrict__ W0, const u8* __restrict__ W1,
        const u8* __restrict__ seqbP,
        const float* __restrict__ b0, const float* __restrict__ b1,
        u8* __restrict__ h0buf, u8* __restrict__ h1buf,
        const u8* __restrict__ zb,
        float* __restrict__ sqo, unsigned* __restrict__ arr) {
    __shared__ uint4 w1lds[8192];               // 128 KiB W1 slice
    __shared__ _Float16 pA[2 * 16 * 16 * 16];   // 16 KiB L0 partials
    __shared__ _Float16 pB[2 * 16 * 16 * 16];   // 16 KiB L1 partials -> 160 KiB total
    const int jt = blockIdx.x, tid = threadIdx.x;
    const int w = tid >> 6, l = tid & 63;
    const int la = l & 15, kg = l >> 4;
    {
        const uint4* src = (const uint4*)(W1 + (size_t)jt * 131072);
        for (int i = tid; i < 8192; i += 1024) w1lds[i] = src[i];
    }
    // pin W0: tiles jt*2+t, kc2 = w*4..w*4+3
    l64x2 w0pin[8];
#pragma unroll
    for (int t = 0; t < 2; ++t)
#pragma unroll
        for (int i = 0; i < 4; ++i)
            w0pin[t * 4 + i] = *(const l64x2*)(W0 +
                ((size_t)((jt * 2 + t) * 64 + w * 4 + i) * 64 + l) * 16);
    float cr = 0.f;          // cr0 on tid<128, cr1 on tid 128..255
    float bi = 0, bf = 0, bg = 0, bo = 0;
    if (tid < 128) {
        int j = jt * 8 + (tid & 7);
        bi = b0[j]; bf = b0[FDIM + j]; bg = b0[2 * FDIM + j]; bo = b0[3 * FDIM + j];
    } else if (tid < 256) {
        int j = jt * 8 + (tid & 7);
        bi = b1[j]; bf = b1[FDIM + j]; bg = b1[2 * FDIM + j]; bo = b1[3 * FDIM + j];
    }
    __syncthreads();

    unsigned* bs = arr;
    const l64x2* bbA = (const l64x2*)w1lds + ((size_t)(w * 4) * 64 + l);
    const l64x2* bbB = bbA + (size_t)64 * 64;
    const f32x4 z = {0.f, 0.f, 0.f, 0.f};
    const size_t wl = (size_t)w * 4096 + (size_t)l * 8;        // waves 0-7
    const size_t wh = (size_t)(w - 8) * 4096 + (size_t)l * 8;  // waves 8-15
#define H0(s) (h0buf + (size_t)(s) * 32768)
#define H1(s) (h1buf + (size_t)(s) * 32768)

    long f0[8], f1[8];

    // ---- stage 0: L0[0] (x = seqbP[0], h = zeros); no leading barrier ----
    {
        load8_plain((w < 8) ? seqbP + wl : zb + wh, f0);
        vm_wait0();
        f32x4 t0 = z, t1 = z;
        mma8_reg(f0, w0pin, t0); mma8_reg(f0, w0pin + 4, t1);
        store_frag(pA, 0, w, kg, la, t0);
        store_frag(pA, 1, w, kg, la, t1);
        sync_lds();
        if (tid < 128)
            cell_tail16(pA, jt, tid, bi, bf, bg, bo, cr, H0(0), nullptr);
    }
    // ---- fwd stages s=0..30: L0[s+1] + L1[s], one sync, parallel tails ----
    for (int s = 0; s <= 30; ++s) {
        if (w < 8) load8_plain(seqbP + (size_t)(s + 1) * 32768 + wl, f0); // static, pre-bar
        grid_bar(bs); bs += 256;
        if (w >= 8) {
            load8_plain(H0(s) + wh, f0);                 // fresh h0[s]
            load8_plain((s ? H1(s - 1) : zb) + wh, f1);  // fresh h1[s-1]
        } else {
            load8_plain(H0(s) + wl, f1);                 // fresh h0[s]
        }
        vm_wait0();
        f32x4 q00 = z, q01 = z, q10 = z, q11 = z;
        mma8_reg(f0, w0pin, q00); mma8_reg(f0, w0pin + 4, q01);
        mma8_lds(f1, bbA, q10);   mma8_lds(f1, bbB, q11);
        store_frag(pA, 0, w, kg, la, q00);
        store_frag(pA, 1, w, kg, la, q01);
        store_frag(pB, 0, w, kg, la, q10);
        store_frag(pB, 1, w, kg, la, q11);
        sync_lds();
        if (tid < 128)
            cell_tail16(pA, jt, tid, bi, bf, bg, bo, cr, H0(s + 1), nullptr);
        else if (tid < 256)
            cell_tail16(pB, jt, tid - 128, bi, bf, bg, bo, cr, H1(s), nullptr);
    }
    // ---- L1[31]: first recorded output; pre-issue AR L0[32]'s stale half ----
    {
        grid_bar(bs); bs += 256;
        load8_plain((w < 8) ? H0(31) + wl : H1(30) + wh, f1);   // both fresh
        vm_wait0();
        f32x4 t0 = z, t1 = z;
        mma8_lds(f1, bbA, t0); mma8_lds(f1, bbB, t1);
        if (w >= 8) load8_plain(H0(31) + wh, f0);               // stale for L0[32]
        store_frag(pB, 0, w, kg, la, t0);
        store_frag(pB, 1, w, kg, la, t1);
        sync_lds();
        if (tid >= 128 && tid < 256)
            cell_tail16(pB, jt, tid - 128, bi, bf, bg, bo, cr, H1(31), sqo);
    }
    // ---- AR region s=32..62: 2 phases/step, stale halves pre-issued ----
    for (int s = 32; s < 63; ++s) {
        // L0[s]: x = h1[s-1] (fresh, w<8); h0[s-1] (stale, w>=8, pre-issued)
        grid_bar(bs); bs += 256;
        if (w < 8) load8_plain(H1(s - 1) + wl, f0);
        vm_wait0();
        {
            f32x4 t0 = z, t1 = z;
            mma8_reg(f0, w0pin, t0); mma8_reg(f0, w0pin + 4, t1);
            if (w >= 8) load8_plain(H1(s - 1) + wh, f1);        // stale for L1[s]
            store_frag(pA, 0, w, kg, la, t0);
            store_frag(pA, 1, w, kg, la, t1);
            sync_lds();
            if (tid < 128)
                cell_tail16(pA, jt, tid, bi, bf, bg, bo, cr, H0(s), nullptr);
        }
        // L1[s]: h0[s] (fresh, w<8); h1[s-1] (stale, w>=8, pre-issued)
        grid_bar(bs); bs += 256;
        if (w < 8) load8_plain(H0(s) + wl, f1);
        vm_wait0();
        {
            f32x4 t0 = z, t1 = z;
            mma8_lds(f1, bbA, t0); mma8_lds(f1, bbB, t1);
            if (w >= 8 && s != 62) load8_plain(H0(s) + wh, f0); // stale for L0[s+1]
            store_frag(pB, 0, w, kg, la, t0);
            store_frag(pB, 1, w, kg, la, t1);
            sync_lds();
            if (tid >= 128 && tid < 256)
                cell_tail16(pB, jt, tid - 128, bi, bf, bg, bo, cr, H1(s),
                            sqo + (size_t)(s - 31) * NB * FDIM);
        }
    }
#undef H0
#undef H1
}

// copy latent -> out[:, :, 0:32, :]
__global__ void copy_lat(const float* __restrict__ latent, float* __restrict__ out) {
    size_t i = (size_t)blockIdx.x * blockDim.x + threadIdx.x;
    if (i >= (size_t)1048576) return;
    size_t blk = i >> 8;
    size_t within = i & 255;
    float4 v = ((const float4*)latent)[i];
    ((float4*)out)[blk * 512 + within] = v;
}

// gen half: out[n][c][32+t][h] = sum_cb seq_out[t][n][h*64+cb]*w_out[c][cb] + b_out[c]
__global__ __launch_bounds__(256) void gen_out(const float* __restrict__ seq_out,
                        const float* __restrict__ w_out, const float* __restrict__ b_out,
                        float* __restrict__ out) {
    __shared__ float row[32 * 65];
    int b = blockIdx.x; int n = b >> 5, t = b & 31;
    const float* src = seq_out + ((size_t)t * NB + n) * FDIM;
    for (int i = threadIdx.x; i < FDIM; i += 256)
        row[(i >> 6) * 65 + (i & 63)] = src[i];
    __syncthreads();
    for (int it = 0; it < 32; ++it) {
        int o = it * 256 + threadIdx.x;
        int c = o >> 5, h = o & 31;
        float acc = b_out[c];
#pragma unroll
        for (int cb = 0; cb < CBD; ++cb) acc += row[h * 65 + cb] * w_out[c * CBD + cb];
        out[(((size_t)n * CDIM + c) * 64 + 32 + t) * HGT + h] = acc;
    }
}

extern "C" void kernel_launch(void* const* d_in, const int* in_sizes, int n_in,
                              void* d_out, int out_size, void* d_ws, size_t ws_size,
                              hipStream_t stream) {
    const float* latent = (const float*)d_in[0];
    const float* w_in   = (const float*)d_in[1];
    const float* b_in   = (const float*)d_in[2];
    const float* w_ih0  = (const float*)d_in[3];
    const float* w_hh0  = (const float*)d_in[4];
    const float* b_ih0  = (const float*)d_in[5];
    const float* b_hh0  = (const float*)d_in[6];
    const float* w_ih1  = (const float*)d_in[7];
    const float* w_hh1  = (const float*)d_in[8];
    const float* b_ih1  = (const float*)d_in[9];
    const float* b_hh1  = (const float*)d_in[10];
    const float* w_out  = (const float*)d_in[11];
    const float* b_out  = (const float*)d_in[12];
    float* out = (float*)d_out;
    char* ws = (char*)d_ws;

    size_t off = 0;
    u8*    W0   = (u8*)(ws + off); off += (size_t)512 * 65536;             // 32 MiB
    u8*    W1   = (u8*)(ws + off); off += (size_t)512 * 65536;             // 32 MiB
    u8*    seqbP= (u8*)(ws + off); off += (size_t)WSEQ * 32768;            // 1 MiB
    float* sqo  = (float*)(ws + off); off += (size_t)WSEQ * NB * FDIM * 4; // 4 MiB
    u8*    h0buf= (u8*)(ws + off); off += (size_t)64 * 32768;              // 2 MiB
    u8*    h1buf= (u8*)(ws + off); off += (size_t)64 * 32768;              // 2 MiB
    char*  zbase = ws + off;
    u8*    zb   = (u8*)(ws + off); off += 32768;                           // zeros
    unsigned* arr = (unsigned*)(ws + off); off += (size_t)96 * 1024;       // 96 KiB (94 used)
    size_t zbytes = (size_t)(ws + off - zbase);
    float* b0 = (float*)(ws + off); off += (size_t)GDIM * 4;
    float* b1 = (float*)(ws + off); off += (size_t)GDIM * 4;

    if (ws_size < off) {
        hipMemsetAsync(d_out, 0, (size_t)out_size * 4, stream);
        return;
    }

    hipMemsetAsync(zbase, 0, zbytes, stream);
    pack_w<<<1024, 256, 0, stream>>>(w_ih0, w_hh0, w_ih1, w_hh1, W0, W1);
    bias_k<<<64, 256, 0, stream>>>(b_ih0, b_hh0, b_ih1, b_hh1, b0, b1);
    conv_in<<<512, 256, 0, stream>>>(latent, w_in, b_in, seqbP);
    recurrence<<<256, 1024, 0, stream>>>(W0, W1, seqbP, b0, b1,
                                         h0buf, h1buf, zb, sqo, arr);
    copy_lat<<<4096, 256, 0, stream>>>(latent, out);
    gen_out<<<512, 256, 0, stream>>>(sqo, w_out, b_out, out);
}

// Round 15
// 700.098 us; speedup vs baseline: 1.5465x; 1.1566x over previous
//
#include <hip/hip_runtime.h>
#include <hip/hip_bf16.h>

#define NB   16      // batch
#define FDIM 2048    // lstm hidden
#define GDIM 8192    // 4*FDIM gates
#define WSEQ 32      // seq len
#define CDIM 256
#define CBD  64
#define HGT  32

#define AGENTSC __HIP_MEMORY_SCOPE_AGENT

typedef float f32x4 __attribute__((ext_vector_type(4)));
typedef long  l64x2 __attribute__((ext_vector_type(2)));
typedef _Float16 f16x4 __attribute__((ext_vector_type(4)));
typedef unsigned char u8;

__device__ __forceinline__ float sigf(float x) { return 1.f / (1.f + __expf(-x)); }

__device__ __forceinline__ u8 f32_to_fp8(float f) {
    int w = __builtin_amdgcn_cvt_pk_fp8_f32(f, f, 0, 0);
    return (u8)(w & 0xff);
}

// ---------------------------------------------------------------------------
// Coalesced weight pack -> fp8 e4m3 (layout as R5-R14), 4 rows in flight.
// W[tile][kc2][lane][16B]; bytes0-7 = frag kc=2kc2, 8-15 = kc=2kc2+1;
// frag byte i of (kc,lane): k = kc*32+(lane>>4)*8+i, col = lane&15.
// ---------------------------------------------------------------------------
__global__ __launch_bounds__(256) void pack_w(
        const float* __restrict__ wih0, const float* __restrict__ whh0,
        const float* __restrict__ wih1, const float* __restrict__ whh1,
        u8* __restrict__ W0, u8* __restrict__ W1) {
    __shared__ u8 FW[16][4112];   // [c][k], +16 pad
    int b = blockIdx.x;           // 0..1023
    int mat = b >> 9, tile = b & 511;
    const float* wih = mat ? wih1 : wih0;
    const float* whh = mat ? whh1 : whh0;
    int p = tile & 1, jt = tile >> 1;
    int tid = threadIdx.x;
    for (int it = 0; it < 32; it += 4) {   // 2 src halves x 16 rows, 4-deep ILP
        float4 f[4][2];
#pragma unroll
        for (int r = 0; r < 4; ++r) {
            int c = (it + r) & 15, srcsel = (it + r) >> 4;
            int gate = p * 2 + (c >> 3);
            int rr = gate * FDIM + jt * 8 + (c & 7);
            const float* s = (srcsel ? whh : wih) + (size_t)rr * FDIM + tid * 8;
            f[r][0] = *(const float4*)(s);
            f[r][1] = *(const float4*)(s + 4);
        }
#pragma unroll
        for (int r = 0; r < 4; ++r) {
            int c = (it + r) & 15, srcsel = (it + r) >> 4;
            int w0 = __builtin_amdgcn_cvt_pk_fp8_f32(f[r][0].x, f[r][0].y, 0, 0);
            w0     = __builtin_amdgcn_cvt_pk_fp8_f32(f[r][0].z, f[r][0].w, w0, 1);
            int w1 = __builtin_amdgcn_cvt_pk_fp8_f32(f[r][1].x, f[r][1].y, 0, 0);
            w1     = __builtin_amdgcn_cvt_pk_fp8_f32(f[r][1].z, f[r][1].w, w1, 1);
            *(int2*)&FW[c][srcsel * 2048 + tid * 8] = make_int2(w0, w1);
        }
    }
    __syncthreads();
    u8* base = (mat ? W1 : W0) + (size_t)tile * 65536;
#pragma unroll
    for (int w = 0; w < 16; ++w) {
        int q = w * 256 + tid;            // kc2*64 + lane
        int kc2 = q >> 6, lane = q & 63;
        int c = lane & 15, kg = lane >> 4;
        l64x2 v;
        v.x = *(const long*)&FW[c][kc2 * 64 + kg * 8];
        v.y = *(const long*)&FW[c][kc2 * 64 + 32 + kg * 8];
        *(l64x2*)(base + (size_t)q * 16) = v;
    }
}

__global__ void bias_k(const float* __restrict__ bih0, const float* __restrict__ bhh0,
                       const float* __restrict__ bih1, const float* __restrict__ bhh1,
                       float* __restrict__ b0, float* __restrict__ b1) {
    int i = blockIdx.x * blockDim.x + threadIdx.x;
    if (i < GDIM)            b0[i] = bih0[i] + bhh0[i];
    else if (i < 2 * GDIM) { int j = i - GDIM; b1[j] = bih1[j] + bhh1[j]; }
}

// ---------------------------------------------------------------------------
// 1x1 conv-in; emit seq in PACKED A-fragment layout:
//   seqbP[t] : [64 kc][64 lane][8B], byte i of (kc,lane): k = kc*32+(lane>>4)*8+i
// ---------------------------------------------------------------------------
__global__ __launch_bounds__(256) void conv_in(const float* __restrict__ latent,
                        const float* __restrict__ w_in, const float* __restrict__ b_in,
                        u8* __restrict__ seqbP) {
    __shared__ float lat[CDIM * HGT]; // [c][h] 32 KiB
    __shared__ float hv[FDIM];        // 8 KiB
    int b = blockIdx.x; int n = b >> 5; int t = b & 31;
    int tid = threadIdx.x;
    for (int i = 0; i < 32; ++i) {
        int flat = i * 256 + tid;         // c*32+h
        int c = flat >> 5, h = flat & 31;
        lat[flat] = latent[(((size_t)n * CDIM + c) * WSEQ + t) * HGT + h];
    }
    __syncthreads();
    int cb = tid & 63;
    int hb = tid >> 6;
    float acc[8];
#pragma unroll
    for (int k = 0; k < 8; ++k) acc[k] = b_in[cb];
    for (int c = 0; c < CDIM; ++c) {
        float wv = w_in[cb * CDIM + c];
#pragma unroll
        for (int k = 0; k < 8; ++k) acc[k] += lat[c * HGT + (hb + k * 4)] * wv;
    }
#pragma unroll
    for (int k = 0; k < 8; ++k) hv[k * 256 + tid] = acc[k];   // hv[f], f = h*64+cb
    __syncthreads();
    union { u8 by[8]; long l; } pk;
#pragma unroll
    for (int i = 0; i < 8; ++i) pk.by[i] = f32_to_fp8(hv[tid * 8 + i]);
    *(long*)(seqbP + (size_t)t * 32768 + (tid >> 2) * 512 + (tid & 3) * 128 + n * 8) = pk.l;
}

// ---------------------------------------------------------------------------
// Async 8x8B PLAIN (L2-cached) load cluster, chunk stride 512B, no waits.
// Safe: every activation address is written exactly once (fresh per stage)
// before its consuming stage -> no stale L2 lines possible.
// ---------------------------------------------------------------------------
__device__ __forceinline__ void load8_plain(const u8* p, long* f) {
    asm volatile("global_load_dwordx2 %0, %1, off"             : "=v"(f[0]) : "v"(p));
    asm volatile("global_load_dwordx2 %0, %1, off offset:512"  : "=v"(f[1]) : "v"(p));
    asm volatile("global_load_dwordx2 %0, %1, off offset:1024" : "=v"(f[2]) : "v"(p));
    asm volatile("global_load_dwordx2 %0, %1, off offset:1536" : "=v"(f[3]) : "v"(p));
    asm volatile("global_load_dwordx2 %0, %1, off offset:2048" : "=v"(f[4]) : "v"(p));
    asm volatile("global_load_dwordx2 %0, %1, off offset:2560" : "=v"(f[5]) : "v"(p));
    asm volatile("global_load_dwordx2 %0, %1, off offset:3072" : "=v"(f[6]) : "v"(p));
    asm volatile("global_load_dwordx2 %0, %1, off offset:3584" : "=v"(f[7]) : "v"(p));
}
// 16-chunk window = two 8-chunk clusters (13-bit offset limit)
__device__ __forceinline__ void load16_plain(const u8* p, long* f) {
    load8_plain(p, f);
    load8_plain(p + 4096, f + 8);
}

__device__ __forceinline__ void vm_wait0() {
    asm volatile("s_waitcnt vmcnt(0)" ::: "memory");
    __builtin_amdgcn_sched_barrier(0);
}
__device__ __forceinline__ void vm_wait16() {
    asm volatile("s_waitcnt vmcnt(16)" ::: "memory");
    __builtin_amdgcn_sched_barrier(0);
}

// lgkm-only block sync (does NOT drain vmcnt)
__device__ __forceinline__ void sync_lds() {
    asm volatile("s_waitcnt lgkmcnt(0)" ::: "memory");
    __builtin_amdgcn_s_barrier();
    asm volatile("" ::: "memory");
}

__device__ __forceinline__ f32x4 mfma8(long a, long b, f32x4 acc) {
    return __builtin_amdgcn_mfma_f32_16x16x32_fp8_fp8(a, b, acc, 0, 0, 0);
}

// 16 chunks against register-pinned B (8 l64x2)
__device__ __forceinline__ void mma16_reg(const long* f, const l64x2* b, f32x4& acc) {
#pragma unroll
    for (int i = 0; i < 8; ++i) {
        acc = mfma8(f[2 * i],     b[i].x, acc);
        acc = mfma8(f[2 * i + 1], b[i].y, acc);
    }
}
// 16 chunks against LDS B (stride 64 l64x2 per kc2)
__device__ __forceinline__ void mma16_lds(const long* f, const l64x2* bb, f32x4& acc) {
#pragma unroll
    for (int i = 0; i < 8; ++i) {
        l64x2 bl = bb[(size_t)i * 64];
        acc = mfma8(f[2 * i],     bl.x, acc);
        acc = mfma8(f[2 * i + 1], bl.y, acc);
    }
}

// fp16 partials, PAD-20 (R12-proven conflict-free): P[t][w(8)][col la][20]
__device__ __forceinline__ void store_frag(_Float16* P, int t, int w,
                                           int kg, int la, f32x4 acc) {
    f16x4 h;
#pragma unroll
    for (int q = 0; q < 4; ++q) h[q] = (_Float16)acc[q];
    *(f16x4*)&P[(((t * 8 + w) * 16) + la) * 20 + kg * 4] = h;
}

// LSTM cell tail: 8-deep fp16 partial reduce; cell state in regs; h -> one
// fresh 32KiB buffer via sc1 byte store. t2 = local idx 0..127.
__device__ __forceinline__ void cell_tail8(const _Float16* P, int jt, int t2,
        float bi, float bf, float bg, float bo, float& cr,
        u8* hOut, float* seqSlot) {
    int m = t2 >> 3, jj = t2 & 7;
    float gi = 0.f, gf = 0.f, gg = 0.f, go = 0.f;
#pragma unroll
    for (int w2 = 0; w2 < 8; ++w2) {
        int i0 = (w2 * 16 + jj) * 20 + m;
        gi += (float)P[i0];
        gf += (float)P[i0 + 160];
        gg += (float)P[i0 + 2560];
        go += (float)P[i0 + 2720];
    }
    float cn = sigf(gf + bf) * cr + sigf(gi + bi) * tanhf(gg + bg);
    float h  = sigf(go + bo) * tanhf(cn);
    cr = cn;
    u8 hb = f32_to_fp8(h);
    int pos = (jt >> 2) * 512 + (jt & 3) * 128 + t2;
    __hip_atomic_store(hOut + pos, hb, __ATOMIC_RELAXED, AGENTSC);
    if (seqSlot)
        __hip_atomic_store(seqSlot + m * FDIM + jt * 8 + jj, h,
                           __ATOMIC_RELAXED, AGENTSC);
}

// ---------------------------------------------------------------------------
// Store-slot grid barrier: per-stage arr[k][256]. Arrival = ONE sc1 store.
// Wave 0 polls all 256 slots (1 dwordx4 per lane). Entry __syncthreads
// drains each wave's sc1 h-stores (compiler emits vmcnt(0) before s_barrier).
// ---------------------------------------------------------------------------
__device__ __forceinline__ void grid_bar(unsigned* slots) {
    __syncthreads();
    if (threadIdx.x < 64) {
        if (threadIdx.x == 0) {
            unsigned one = 1u;
            const unsigned* p = slots + blockIdx.x;
            asm volatile("global_store_dword %0, %1, off sc1"
                         :: "v"(p), "v"(one) : "memory");
        }
        const uint4* q = (const uint4*)slots + threadIdx.x;
        int guard = 0;
        while (++guard < (1 << 22)) {
            uint4 v;
            asm volatile("global_load_dwordx4 %0, %1, off sc1"
                         : "=v"(v) : "v"(q) : "memory");
            asm volatile("s_waitcnt vmcnt(0)" ::: "memory");
            if (__all((v.x & v.y & v.z & v.w) != 0u)) break;
            __builtin_amdgcn_s_sleep(1);
        }
    }
    __syncthreads();
}

// ---------------------------------------------------------------------------
// Persistent recurrence. 256 blocks x 512 thr (8 waves, 1 block/CU). Block jt
// owns features jt*8..jt*8+7 for all 4 gates. Wave w (0..7) covers K chunks
// w*16..w*16+15 for both gate-pair tiles and BOTH layers (x-half waves 0-3,
// h-half waves 4-7). W0 slice pinned in regs (32 VGPR, cap 256 via
// launch_bounds(512,2)); W1 slice in LDS (128 KiB). Two PAD-20 partial sets
// (10 KiB each) -> 148 KiB LDS, zero bank conflicts (R12-proven layout).
// Single-sync stages with PARALLEL cell tails (tid<128: L0/cr0, tid 128-255:
// L1/cr1). Activations rotate through per-stage fresh buffers (plain
// L2-cached reads, sc1 writes). AR: stale half pre-issued a phase early.
// ---------------------------------------------------------------------------
__global__ __launch_bounds__(512, 2) void recurrence(
        const u8* __restrict__ W0, const u8* __restrict__ W1,
        const u8* __restrict__ seqbP,
        const float* __restrict__ b0, const float* __restrict__ b1,
        u8* __restrict__ h0buf, u8* __restrict__ h1buf,
        const u8* __restrict__ zb,
        float* __restrict__ sqo, unsigned* __restrict__ arr) {
    __shared__ uint4 w1lds[8192];              // 128 KiB W1 slice
    __shared__ _Float16 pA[2 * 8 * 16 * 20];   // 10 KiB L0 partials (pad-20)
    __shared__ _Float16 pB[2 * 8 * 16 * 20];   // 10 KiB L1 partials
    const int jt = blockIdx.x, tid = threadIdx.x;
    const int w = tid >> 6, l = tid & 63;
    const int la = l & 15, kg = l >> 4;
    {
        const uint4* src = (const uint4*)(W1 + (size_t)jt * 131072);
        for (int i = tid; i < 8192; i += 512) w1lds[i] = src[i];
    }
    // pin W0: tiles jt*2+t, kc2 = w*8..w*8+7  (16 l64x2 = 32 VGPR)
    l64x2 w0pin[16];
#pragma unroll
    for (int t = 0; t < 2; ++t)
#pragma unroll
        for (int i = 0; i < 8; ++i)
            w0pin[t * 8 + i] = *(const l64x2*)(W0 +
                ((size_t)((jt * 2 + t) * 64 + w * 8 + i) * 64 + l) * 16);
    float cr = 0.f;          // cr0 on tid<128, cr1 on tid 128..255
    float bi = 0, bf = 0, bg = 0, bo = 0;
    if (tid < 128) {
        int j = jt * 8 + (tid & 7);
        bi = b0[j]; bf = b0[FDIM + j]; bg = b0[2 * FDIM + j]; bo = b0[3 * FDIM + j];
    } else if (tid < 256) {
        int j = jt * 8 + (tid & 7);
        bi = b1[j]; bf = b1[FDIM + j]; bg = b1[2 * FDIM + j]; bo = b1[3 * FDIM + j];
    }
    __syncthreads();

    unsigned* bs = arr;
    const l64x2* bbA = (const l64x2*)w1lds + ((size_t)(w * 8) * 64 + l);  // W1 tile0
    const l64x2* bbB = bbA + (size_t)64 * 64;                              // W1 tile1
    const f32x4 z = {0.f, 0.f, 0.f, 0.f};
    const size_t wl = (size_t)w * 8192 + (size_t)l * 8;        // waves 0-3 (x half)
    const size_t wh = (size_t)(w - 4) * 8192 + (size_t)l * 8;  // waves 4-7 (h half)
#define H0(s) (h0buf + (size_t)(s) * 32768)
#define H1(s) (h1buf + (size_t)(s) * 32768)

    long f0[16], f1[16];

    // ---- stage 0: L0[0] (x = seqbP[0], h = zeros); no leading barrier ----
    {
        load16_plain((w < 4) ? seqbP + wl : zb + wh, f0);
        vm_wait0();
        f32x4 t0 = z, t1 = z;
        mma16_reg(f0, w0pin, t0); mma16_reg(f0, w0pin + 8, t1);
        store_frag(pA, 0, w, kg, la, t0);
        store_frag(pA, 1, w, kg, la, t1);
        sync_lds();
        if (tid < 128)
            cell_tail8(pA, jt, tid, bi, bf, bg, bo, cr, H0(0), nullptr);
    }
    // ---- fwd stages s=0..30: L0[s+1] + L1[s], one sync, parallel tails ----
    for (int s = 0; s <= 30; ++s) {
        if (w < 4) load16_plain(seqbP + (size_t)(s + 1) * 32768 + wl, f0); // static, pre-bar
        grid_bar(bs); bs += 256;
        if (w >= 4) {
            load16_plain(H0(s) + wh, f0);                 // fresh h0[s]
            load16_plain((s ? H1(s - 1) : zb) + wh, f1);  // fresh h1[s-1]
        } else {
            load16_plain(H0(s) + wl, f1);                 // fresh h0[s]
        }
        vm_wait16();                                      // f0 ready (w>=4); no-op w<4
        f32x4 q00 = z, q01 = z, q10 = z, q11 = z;
        mma16_reg(f0, w0pin, q00); mma16_reg(f0, w0pin + 8, q01);
        vm_wait0();                                       // f1 ready
        mma16_lds(f1, bbA, q10);   mma16_lds(f1, bbB, q11);
        store_frag(pA, 0, w, kg, la, q00);
        store_frag(pA, 1, w, kg, la, q01);
        store_frag(pB, 0, w, kg, la, q10);
        store_frag(pB, 1, w, kg, la, q11);
        sync_lds();
        if (tid < 128)
            cell_tail8(pA, jt, tid, bi, bf, bg, bo, cr, H0(s + 1), nullptr);
        else if (tid < 256)
            cell_tail8(pB, jt, tid - 128, bi, bf, bg, bo, cr, H1(s), nullptr);
    }
    // ---- L1[31]: first recorded output; pre-issue AR L0[32]'s stale half ----
    {
        grid_bar(bs); bs += 256;
        load16_plain((w < 4) ? H0(31) + wl : H1(30) + wh, f1);  // both fresh
        vm_wait0();
        f32x4 t0 = z, t1 = z;
        mma16_lds(f1, bbA, t0); mma16_lds(f1, bbB, t1);
        if (w >= 4) load16_plain(H0(31) + wh, f0);              // stale for L0[32]
        store_frag(pB, 0, w, kg, la, t0);
        store_frag(pB, 1, w, kg, la, t1);
        sync_lds();
        if (tid >= 128 && tid < 256)
            cell_tail8(pB, jt, tid - 128, bi, bf, bg, bo, cr, H1(31), sqo);
    }
    // ---- AR region s=32..62: 2 phases/step, stale halves pre-issued ----
    for (int s = 32; s < 63; ++s) {
        // L0[s]: x = h1[s-1] (fresh, w<4); h0[s-1] (stale, w>=4, pre-issued)
        grid_bar(bs); bs += 256;
        if (w < 4) load16_plain(H1(s - 1) + wl, f0);
        vm_wait0();
        {
            f32x4 t0 = z, t1 = z;
            mma16_reg(f0, w0pin, t0); mma16_reg(f0, w0pin + 8, t1);
            if (w >= 4) load16_plain(H1(s - 1) + wh, f1);       // stale for L1[s]
            store_frag(pA, 0, w, kg, la, t0);
            store_frag(pA, 1, w, kg, la, t1);
            sync_lds();
            if (tid < 128)
                cell_tail8(pA, jt, tid, bi, bf, bg, bo, cr, H0(s), nullptr);
        }
        // L1[s]: h0[s] (fresh, w<4); h1[s-1] (stale, w>=4, pre-issued)
        grid_bar(bs); bs += 256;
        if (w < 4) load16_plain(H0(s) + wl, f1);
        vm_wait0();
        {
            f32x4 t0 = z, t1 = z;
            mma16_lds(f1, bbA, t0); mma16_lds(f1, bbB, t1);
            if (w >= 4 && s != 62) load16_plain(H0(s) + wh, f0); // stale for L0[s+1]
            store_frag(pB, 0, w, kg, la, t0);
            store_frag(pB, 1, w, kg, la, t1);
            sync_lds();
            if (tid >= 128 && tid < 256)
                cell_tail8(pB, jt, tid - 128, bi, bf, bg, bo, cr, H1(s),
                           sqo + (size_t)(s - 31) * NB * FDIM);
        }
    }
#undef H0
#undef H1
}

// copy latent -> out[:, :, 0:32, :]
__global__ void copy_lat(const float* __restrict__ latent, float* __restrict__ out) {
    size_t i = (size_t)blockIdx.x * blockDim.x + threadIdx.x;
    if (i >= (size_t)1048576) return;
    size_t blk = i >> 8;
    size_t within = i & 255;
    float4 v = ((const float4*)latent)[i];
    ((float4*)out)[blk * 512 + within] = v;
}

// gen half: out[n][c][32+t][h] = sum_cb seq_out[t][n][h*64+cb]*w_out[c][cb] + b_out[c]
__global__ __launch_bounds__(256) void gen_out(const float* __restrict__ seq_out,
                        const float* __restrict__ w_out, const float* __restrict__ b_out,
                        float* __restrict__ out) {
    __shared__ float row[32 * 65];
    int b = blockIdx.x; int n = b >> 5, t = b & 31;
    const float* src = seq_out + ((size_t)t * NB + n) * FDIM;
    for (int i = threadIdx.x; i < FDIM; i += 256)
        row[(i >> 6) * 65 + (i & 63)] = src[i];
    __syncthreads();
    for (int it = 0; it < 32; ++it) {
        int o = it * 256 + threadIdx.x;
        int c = o >> 5, h = o & 31;
        float acc = b_out[c];
#pragma unroll
        for (int cb = 0; cb < CBD; ++cb) acc += row[h * 65 + cb] * w_out[c * CBD + cb];
        out[(((size_t)n * CDIM + c) * 64 + 32 + t) * HGT + h] = acc;
    }
}

extern "C" void kernel_launch(void* const* d_in, const int* in_sizes, int n_in,
                              void* d_out, int out_size, void* d_ws, size_t ws_size,
                              hipStream_t stream) {
    const float* latent = (const float*)d_in[0];
    const float* w_in   = (const float*)d_in[1];
    const float* b_in   = (const float*)d_in[2];
    const float* w_ih0  = (const float*)d_in[3];
    const float* w_hh0  = (const float*)d_in[4];
    const float* b_ih0  = (const float*)d_in[5];
    const float* b_hh0  = (const float*)d_in[6];
    const float* w_ih1  = (const float*)d_in[7];
    const float* w_hh1  = (const float*)d_in[8];
    const float* b_ih1  = (const float*)d_in[9];
    const float* b_hh1  = (const float*)d_in[10];
    const float* w_out  = (const float*)d_in[11];
    const float* b_out  = (const float*)d_in[12];
    float* out = (float*)d_out;
    char* ws = (char*)d_ws;

    size_t off = 0;
    u8*    W0   = (u8*)(ws + off); off += (size_t)512 * 65536;             // 32 MiB
    u8*    W1   = (u8*)(ws + off); off += (size_t)512 * 65536;             // 32 MiB
    u8*    seqbP= (u8*)(ws + off); off += (size_t)WSEQ * 32768;            // 1 MiB
    float* sqo  = (float*)(ws + off); off += (size_t)WSEQ * NB * FDIM * 4; // 4 MiB
    u8*    h0buf= (u8*)(ws + off); off += (size_t)64 * 32768;              // 2 MiB
    u8*    h1buf= (u8*)(ws + off); off += (size_t)64 * 32768;              // 2 MiB
    char*  zbase = ws + off;
    u8*    zb   = (u8*)(ws + off); off += 32768;                           // zeros
    unsigned* arr = (unsigned*)(ws + off); off += (size_t)96 * 1024;       // 96 KiB (94 used)
    size_t zbytes = (size_t)(ws + off - zbase);
    float* b0 = (float*)(ws + off); off += (size_t)GDIM * 4;
    float* b1 = (float*)(ws + off); off += (size_t)GDIM * 4;

    if (ws_size < off) {
        hipMemsetAsync(d_out, 0, (size_t)out_size * 4, stream);
        return;
    }

    hipMemsetAsync(zbase, 0, zbytes, stream);
    pack_w<<<1024, 256, 0, stream>>>(w_ih0, w_hh0, w_ih1, w_hh1, W0, W1);
    bias_k<<<64, 256, 0, stream>>>(b_ih0, b_hh0, b_ih1, b_hh1, b0, b1);
    conv_in<<<512, 256, 0, stream>>>(latent, w_in, b_in, seqbP);
    recurrence<<<256, 512, 0, stream>>>(W0, W1, seqbP, b0, b1,
                                        h0buf, h1buf, zb, sqo, arr);
    copy_lat<<<4096, 256, 0, stream>>>(latent, out);
    gen_out<<<512, 256, 0, stream>>>(sqo, w_out, b_out, out);
}